// Round 1
// baseline (1353.093 us; speedup 1.0000x reference)
//
#include <hip/hip_runtime.h>

// Conv2d 3x3, stride 1, pad 1, dilation 1.
// x: [32, 18, 256, 256] fp32, w: [64, 18, 3, 3] fp32, bias: [64] fp32
// out: [32, 64, 256, 256] fp32
//
// Structure: block = 256 threads = 4 waves.
//   - Weights (162*64 fp32 = 41.5 KB) staged in LDS as [k][oc] so a wave's 16
//     consecutive oc are 4x ds_read_b128, broadcast (same addr all lanes).
//   - Each wave handles 16 output channels (ocBase = wave*16).
//   - Lanes = 64 output columns; each thread computes 4 output rows x 16 oc.
//   - x read directly from global per ic (coalesced, L1/L2-served reuse).

#define N_  32
#define IC_ 18
#define H_  256
#define W_  256
#define OC_ 64
#define KW_TOT (IC_ * 9)          // 162 taps per oc

__global__ __launch_bounds__(256, 3)
void conv3x3_kernel(const float* __restrict__ x,
                    const float* __restrict__ wgt,
                    const float* __restrict__ bias,
                    float* __restrict__ out) {
    __shared__ float wS[KW_TOT * OC_];   // [k][oc], k = (ic*3+kh)*3+kw

    const int tid = threadIdx.x;

    // Stage weights: global [oc][k] -> LDS [k][oc] (done once, 10368 elems).
    for (int i = tid; i < KW_TOT * OC_; i += 256) {
        const int k  = i >> 6;           // 64 oc
        const int oc = i & 63;
        wS[i] = wgt[oc * KW_TOT + k];
    }
    __syncthreads();

    const int tx     = tid & 63;         // output column within tile
    const int wv     = tid >> 6;         // wave id 0..3
    const int ocBase = wv * 16;
    const int w0     = blockIdx.x * 64;  // tile col origin
    const int h0     = blockIdx.y * 4;   // tile row origin
    const int n      = blockIdx.z;

    float acc[4][16];
    #pragma unroll
    for (int o = 0; o < 16; ++o) {
        const float b = bias[ocBase + o];   // wave-uniform -> s_load
        #pragma unroll
        for (int ty = 0; ty < 4; ++ty) acc[ty][o] = b;
    }

    const float* xn = x + (size_t)n * IC_ * H_ * W_;

    for (int ic = 0; ic < IC_; ++ic) {
        const float* xc = xn + ic * (H_ * W_);

        // Register window: 6 rows x 3 cols of x around this lane's column.
        float xv[6][3];
        #pragma unroll
        for (int r = 0; r < 6; ++r) {
            const int gh = h0 - 1 + r;
            const bool rowOK = (unsigned)gh < (unsigned)H_;
            #pragma unroll
            for (int kw = 0; kw < 3; ++kw) {
                const int gw = w0 - 1 + tx + kw;
                const bool ok = rowOK && ((unsigned)gw < (unsigned)W_);
                xv[r][kw] = ok ? xc[gh * W_ + gw] : 0.0f;
            }
        }

        #pragma unroll
        for (int kh = 0; kh < 3; ++kh) {
            #pragma unroll
            for (int kw = 0; kw < 3; ++kw) {
                const float* wp = &wS[((ic * 3 + kh) * 3 + kw) * OC_ + ocBase];
                float wr[16];
                #pragma unroll
                for (int o = 0; o < 16; ++o) wr[o] = wp[o];  // 4x ds_read_b128 broadcast
                #pragma unroll
                for (int ty = 0; ty < 4; ++ty) {
                    const float xs = xv[ty + kh][kw];
                    #pragma unroll
                    for (int o = 0; o < 16; ++o)
                        acc[ty][o] = fmaf(xs, wr[o], acc[ty][o]);
                }
            }
        }
    }

    // Epilogue: coalesced stores (lanes = consecutive columns).
    #pragma unroll
    for (int o = 0; o < 16; ++o) {
        const int oc = ocBase + o;
        float* op = out + (((size_t)n * OC_ + oc) * H_ + h0) * (size_t)W_ + w0 + tx;
        #pragma unroll
        for (int ty = 0; ty < 4; ++ty)
            op[ty * W_] = acc[ty][o];
    }
}

extern "C" void kernel_launch(void* const* d_in, const int* in_sizes, int n_in,
                              void* d_out, int out_size, void* d_ws, size_t ws_size,
                              hipStream_t stream) {
    const float* x    = (const float*)d_in[0];
    const float* wgt  = (const float*)d_in[1];
    const float* bias = (const float*)d_in[2];
    float* out        = (float*)d_out;

    dim3 grid(W_ / 64, H_ / 4, N_);   // 4 x 64 x 32 = 8192 blocks
    dim3 block(256);
    hipLaunchKernelGGL(conv3x3_kernel, grid, block, 0, stream,
                       x, wgt, bias, out);
}